// Round 1
// baseline (570.879 us; speedup 1.0000x reference)
//
#include <hip/hip_runtime.h>

// LSTM: B=8192, T=512, I=3, H=25, then linear [H]->[1].
// Mapping: 1 thread per (batch, hidden unit), computing all 4 gates (i,f,g,o)
// for that unit. 32 lanes per batch (25 active). Block = 256 threads = 8 batches.
// h state double-buffered in LDS (broadcast reads, 1 barrier/step); c in regs.
// Full x for the block's 8 batches staged in LDS up front (48 KB, coalesced).

#define BATCH 8192
#define TSTEPS 512
#define ISZ 3
#define HSZ 25
#define NB 8            // batches per block
#define BLK 256
#define HPAD 28         // h row padded for float4 alignment

__device__ __forceinline__ float fast_sigmoid(float x) {
    // 1 / (1 + 2^(-x*log2e))
    float e = __builtin_amdgcn_exp2f(-1.442695040888963f * x);
    return __builtin_amdgcn_rcpf(1.0f + e);
}
__device__ __forceinline__ float fast_tanh(float x) {
    // tanh(x) = 2*sigmoid(2x) - 1
    return fmaf(2.0f, fast_sigmoid(2.0f * x), -1.0f);
}

__global__ __launch_bounds__(BLK) void lstm_kernel(
    const float* __restrict__ x,      // [B, T, I]
    const float* __restrict__ w_ih,   // [4H, I]
    const float* __restrict__ w_hh,   // [4H, H]
    const float* __restrict__ b_ih,   // [4H]
    const float* __restrict__ b_hh,   // [4H]
    const float* __restrict__ w_lin,  // [1, H]
    const float* __restrict__ b_lin,  // [1]
    float* __restrict__ out)          // [B, 1]
{
    __shared__ float x_s[NB * TSTEPS * ISZ];   // 48 KB
    __shared__ float h_s[2][NB][HPAD];         // double-buffered hidden state

    const int tid = threadIdx.x;
    const int sub = tid >> 5;        // which of the 8 batches in this block
    const int j   = tid & 31;        // hidden-unit index (active if j < 25)
    const int jj  = (j < HSZ) ? j : (HSZ - 1);
    const int b   = blockIdx.x * NB + sub;

    // ---- stage x for all 8 batches (contiguous in global): 3072 float4 ----
    {
        const float4* xg = (const float4*)(x + (size_t)blockIdx.x * (NB * TSTEPS * ISZ));
        float4* xs4 = (float4*)x_s;
        #pragma unroll
        for (int i = 0; i < (NB * TSTEPS * ISZ / 4) / BLK; ++i)  // 12 iters
            xs4[tid + i * BLK] = xg[tid + i * BLK];
    }
    // ---- zero both h buffers ----
    for (int i = tid; i < 2 * NB * HPAD; i += BLK)
        ((float*)h_s)[i] = 0.0f;

    // ---- per-thread weights: 4 gate rows for hidden unit jj ----
    float wih[4][ISZ], whh[4][HSZ], bias[4];
    #pragma unroll
    for (int g = 0; g < 4; ++g) {
        const int r = g * HSZ + jj;
        bias[g] = b_ih[r] + b_hh[r];
        #pragma unroll
        for (int k = 0; k < ISZ; ++k) wih[g][k] = w_ih[r * ISZ + k];
        #pragma unroll
        for (int k = 0; k < HSZ; ++k) whh[g][k] = w_hh[r * HSZ + k];
    }
    const float wl = w_lin[jj];
    const float bl = b_lin[0];

    __syncthreads();

    float c = 0.0f, hval = 0.0f;
    const float* __restrict__ xrow = &x_s[sub * (TSTEPS * ISZ)];
    float* const hb0 = &h_s[0][sub][0];
    float* const hb1 = &h_s[1][sub][0];

    auto step = [&](int t, const float* __restrict__ hr, float* __restrict__ hw) {
        // broadcast-load h (same address across the 32-lane group)
        float hreg[HSZ];
        const float4* h4 = (const float4*)hr;
        #pragma unroll
        for (int q = 0; q < 6; ++q) {
            float4 v = h4[q];
            hreg[4 * q + 0] = v.x; hreg[4 * q + 1] = v.y;
            hreg[4 * q + 2] = v.z; hreg[4 * q + 3] = v.w;
        }
        hreg[24] = hr[24];

        const float x0 = xrow[t * ISZ + 0];
        const float x1 = xrow[t * ISZ + 1];
        const float x2 = xrow[t * ISZ + 2];

        float acc[4];
        #pragma unroll
        for (int g = 0; g < 4; ++g) {
            float a = fmaf(wih[g][0], x0, bias[g]);
            a = fmaf(wih[g][1], x1, a);
            a = fmaf(wih[g][2], x2, a);
            #pragma unroll
            for (int k = 0; k < HSZ; ++k)
                a = fmaf(whh[g][k], hreg[k], a);
            acc[g] = a;
        }
        const float ig = fast_sigmoid(acc[0]);
        const float fg = fast_sigmoid(acc[1]);
        const float gg = fast_tanh(acc[2]);
        const float og = fast_sigmoid(acc[3]);
        c = fmaf(fg, c, ig * gg);
        hval = og * fast_tanh(c);
        if (j < HSZ) hw[j] = hval;
    };

    #pragma unroll 1
    for (int t = 0; t < TSTEPS; t += 2) {
        step(t, hb0, hb1);
        __syncthreads();
        step(t + 1, hb1, hb0);
        __syncthreads();
    }

    // ---- final linear: reduce w_lin . h across the 32-lane group ----
    float v = (j < HSZ) ? wl * hval : 0.0f;
    v += __shfl_xor(v, 16);
    v += __shfl_xor(v, 8);
    v += __shfl_xor(v, 4);
    v += __shfl_xor(v, 2);
    v += __shfl_xor(v, 1);
    if (j == 0) out[b] = v + bl;
}

extern "C" void kernel_launch(void* const* d_in, const int* in_sizes, int n_in,
                              void* d_out, int out_size, void* d_ws, size_t ws_size,
                              hipStream_t stream) {
    const float* x     = (const float*)d_in[0];
    const float* w_ih  = (const float*)d_in[1];
    const float* w_hh  = (const float*)d_in[2];
    const float* b_ih  = (const float*)d_in[3];
    const float* b_hh  = (const float*)d_in[4];
    const float* w_lin = (const float*)d_in[5];
    const float* b_lin = (const float*)d_in[6];
    float* out = (float*)d_out;

    lstm_kernel<<<BATCH / NB, BLK, 0, stream>>>(x, w_ih, w_hh, b_ih, b_hh,
                                                w_lin, b_lin, out);
}

// Round 2
// 495.483 us; speedup vs baseline: 1.1522x; 1.1522x over previous
//
#include <hip/hip_runtime.h>

// LSTM: B=8192, T=512, I=3, H=25, then linear [H]->[1].
// R2: thread = (batch, hidden unit), all 4 gates packed as 2x float2
// accumulators (v_pk_fma_f32). __launch_bounds__(256,1) so all 112 weight
// floats stay in VGPRs (R1's VGPR=80 proved the compiler was re-loading
// weights from global every step). No __syncthreads in the loop: h is
// produced/consumed by the same 32-lane group of one wave, and LDS ops
// within a wave are processed in order -> wave_barrier + mem clobber only.

#define BATCH 8192
#define TSTEPS 512
#define ISZ 3
#define HSZ 25
#define NB 8            // batches per block (2 per wave)
#define BLK 256
#define HPAD 28

typedef float v2f __attribute__((ext_vector_type(2)));

__device__ __forceinline__ float fast_sigmoid(float x) {
    float e = __builtin_amdgcn_exp2f(-1.442695040888963f * x);
    return __builtin_amdgcn_rcpf(1.0f + e);
}
__device__ __forceinline__ float fast_tanh(float x) {
    // tanh(x) = 2*sigmoid(2x) - 1
    return fmaf(2.0f, fast_sigmoid(2.0f * x), -1.0f);
}
__device__ __forceinline__ v2f pk_fma(v2f a, v2f b, v2f c) {
    return __builtin_elementwise_fma(a, b, c);
}

__global__ __launch_bounds__(BLK, 1) void lstm_kernel(
    const float* __restrict__ x,      // [B, T, I]
    const float* __restrict__ w_ih,   // [4H, I]
    const float* __restrict__ w_hh,   // [4H, H]
    const float* __restrict__ b_ih,   // [4H]
    const float* __restrict__ b_hh,   // [4H]
    const float* __restrict__ w_lin,  // [1, H]
    const float* __restrict__ b_lin,  // [1]
    float* __restrict__ out)          // [B, 1]
{
    __shared__ float x_s[NB * TSTEPS * ISZ];   // 48 KB
    __shared__ float h_s[NB][HPAD];            // single-buffered (in-order DS)

    const int tid  = threadIdx.x;
    const int sub  = tid >> 5;        // 32-lane group = one batch
    const int j    = tid & 31;        // hidden unit (active if < 25)
    const int jj   = (j < HSZ) ? j : (HSZ - 1);
    const int wv   = tid >> 6;        // wave id in block
    const int lane = tid & 63;
    const int b    = blockIdx.x * NB + sub;

    // ---- stage this wave's 2 batches of x (contiguous, coalesced) ----
    {
        const float4* xg = (const float4*)(x + ((size_t)blockIdx.x * NB + wv * 2) * (TSTEPS * ISZ));
        float4* xs4 = (float4*)(x_s + wv * 2 * (TSTEPS * ISZ));
        #pragma unroll
        for (int i = 0; i < (2 * TSTEPS * ISZ / 4) / 64; ++i)  // 12 iters
            xs4[lane + i * 64] = xg[lane + i * 64];
    }
    // zero own group's h row (same wave reads it -> in-order DS, no barrier)
    if (j < HPAD) h_s[sub][j] = 0.0f;

    // ---- per-thread weights, gate-pair packed: (i,f) and (g,o) ----
    const int r0 = 0 * HSZ + jj, r1 = 1 * HSZ + jj;
    const int r2 = 2 * HSZ + jj, r3 = 3 * HSZ + jj;
    v2f b01 = { b_ih[r0] + b_hh[r0], b_ih[r1] + b_hh[r1] };
    v2f b23 = { b_ih[r2] + b_hh[r2], b_ih[r3] + b_hh[r3] };
    v2f wi01[ISZ], wi23[ISZ], w01[HSZ], w23[HSZ];
    #pragma unroll
    for (int k = 0; k < ISZ; ++k) {
        wi01[k] = { w_ih[r0 * ISZ + k], w_ih[r1 * ISZ + k] };
        wi23[k] = { w_ih[r2 * ISZ + k], w_ih[r3 * ISZ + k] };
    }
    #pragma unroll
    for (int k = 0; k < HSZ; ++k) {
        w01[k] = { w_hh[r0 * HSZ + k], w_hh[r1 * HSZ + k] };
        w23[k] = { w_hh[r2 * HSZ + k], w_hh[r3 * HSZ + k] };
    }
    const float wl = w_lin[jj];
    const float bl = b_lin[0];

    __asm__ volatile("" ::: "memory");
    __builtin_amdgcn_wave_barrier();

    float c = 0.0f, hval = 0.0f;
    const float* __restrict__ xrow = &x_s[sub * (TSTEPS * ISZ)];
    float* const hrow = &h_s[sub][0];

    #pragma unroll 1
    for (int t = 0; t < TSTEPS; t += 4) {
        // 12 x-values for 4 steps as 3 vector LDS reads
        const float4* xq4 = (const float4*)(xrow + t * ISZ);
        float4 xq0 = xq4[0], xq1 = xq4[1], xq2 = xq4[2];
        const float xv[12] = { xq0.x, xq0.y, xq0.z, xq0.w,
                               xq1.x, xq1.y, xq1.z, xq1.w,
                               xq2.x, xq2.y, xq2.z, xq2.w };
        #pragma unroll
        for (int u = 0; u < 4; ++u) {
            // broadcast-read h (same addresses across the 32-lane group)
            float hreg[HSZ];
            const float4* h4 = (const float4*)hrow;
            #pragma unroll
            for (int q = 0; q < 6; ++q) {
                float4 v = h4[q];
                hreg[4 * q + 0] = v.x; hreg[4 * q + 1] = v.y;
                hreg[4 * q + 2] = v.z; hreg[4 * q + 3] = v.w;
            }
            hreg[24] = hrow[24];

            const float x0 = xv[u * 3 + 0];
            const float x1 = xv[u * 3 + 1];
            const float x2 = xv[u * 3 + 2];

            v2f a01 = b01, a23 = b23;
            a01 = pk_fma(wi01[0], (v2f){x0, x0}, a01);
            a23 = pk_fma(wi23[0], (v2f){x0, x0}, a23);
            a01 = pk_fma(wi01[1], (v2f){x1, x1}, a01);
            a23 = pk_fma(wi23[1], (v2f){x1, x1}, a23);
            a01 = pk_fma(wi01[2], (v2f){x2, x2}, a01);
            a23 = pk_fma(wi23[2], (v2f){x2, x2}, a23);
            #pragma unroll
            for (int k = 0; k < HSZ; ++k) {
                const v2f hh = { hreg[k], hreg[k] };
                a01 = pk_fma(w01[k], hh, a01);
                a23 = pk_fma(w23[k], hh, a23);
            }

            const float iv = fast_sigmoid(a01.x);
            const float fv = fast_sigmoid(a01.y);
            const float gv = fast_tanh(a23.x);
            const float ov = fast_sigmoid(a23.y);
            c = fmaf(fv, c, iv * gv);
            hval = ov * fast_tanh(c);

            if (j < HSZ) hrow[j] = hval;
            __builtin_amdgcn_wave_barrier();
            __asm__ volatile("" ::: "memory");
        }
    }

    // ---- final linear: reduce w_lin . h across the 32-lane group ----
    float v = (j < HSZ) ? wl * hval : 0.0f;
    v += __shfl_xor(v, 16);
    v += __shfl_xor(v, 8);
    v += __shfl_xor(v, 4);
    v += __shfl_xor(v, 2);
    v += __shfl_xor(v, 1);
    if (j == 0) out[b] = v + bl;
}

extern "C" void kernel_launch(void* const* d_in, const int* in_sizes, int n_in,
                              void* d_out, int out_size, void* d_ws, size_t ws_size,
                              hipStream_t stream) {
    const float* x     = (const float*)d_in[0];
    const float* w_ih  = (const float*)d_in[1];
    const float* w_hh  = (const float*)d_in[2];
    const float* b_ih  = (const float*)d_in[3];
    const float* b_hh  = (const float*)d_in[4];
    const float* w_lin = (const float*)d_in[5];
    const float* b_lin = (const float*)d_in[6];
    float* out = (float*)d_out;

    lstm_kernel<<<BATCH / NB, BLK, 0, stream>>>(x, w_ih, w_hh, b_ih, b_hh,
                                                w_lin, b_lin, out);
}

// Round 3
// 451.036 us; speedup vs baseline: 1.2657x; 1.0985x over previous
//
#include <hip/hip_runtime.h>
#include <hip/hip_bf16.h>

// LSTM B=8192,T=512,I=3,H=25 + linear[H->1], via bf16 MFMA (16x16x32).
// One wave per 16-batch tile. D[m=gate-row][n=batch]:
//   A = W' [112x32] bf16, rows r=4u+g (unit-major so one lane's 4 C-regs are
//       i,f,g,o of one unit), cols k: [w_ih(0..2), bias(3), w_hh(4..28), 0pad].
//       7 frags * 4 VGPR, loaded ONCE -> weights register-resident by construction
//       (R1/R2 showed the allocator refuses to keep fp32 weight arrays resident).
//   B = [x0,x1,x2,1,h0..h24,0,0,0] per batch, bf16: h round-trips LDS
//       (scattered ds_write_b16, stride-40-short rows -> <=2-way conflicts);
//       x + 1.0 merged in-register by quad-0 lanes from prefetched global loads.
// No __syncthreads: tile is wave-private, DS ops in-order within a wave.

#define TSTEPS 512
#define ISZ 3
#define HSZ 25
#define NTILES 512          // 8192 / 16
#define TSTRIDE 40          // shorts per batch row in LDS (80 B, 16B-aligned)

typedef __attribute__((ext_vector_type(8))) short bf16x8;
typedef __attribute__((ext_vector_type(4))) float f32x4;

__device__ __forceinline__ float fast_sigmoid(float x) {
    float e = __builtin_amdgcn_exp2f(-1.442695040888963f * x);
    return __builtin_amdgcn_rcpf(1.0f + e);
}
__device__ __forceinline__ float fast_tanh(float x) {
    return fmaf(2.0f, fast_sigmoid(2.0f * x), -1.0f);
}
__device__ __forceinline__ short to_bf16(float v) {
    return __builtin_bit_cast(short, __float2bfloat16(v));
}

__global__ __launch_bounds__(64) void lstm_mfma(
    const float* __restrict__ x,      // [B, T, I]
    const float* __restrict__ w_ih,   // [4H, I]
    const float* __restrict__ w_hh,   // [4H, H]
    const float* __restrict__ b_ih,   // [4H]
    const float* __restrict__ b_hh,   // [4H]
    const float* __restrict__ w_lin,  // [1, H]
    const float* __restrict__ b_lin,  // [1]
    float* __restrict__ out)          // [B, 1]
{
    __shared__ short tile[16 * TSTRIDE];   // bf16 B-columns, one row per batch

    const int lane = threadIdx.x;          // 0..63
    const int n    = lane & 15;            // batch within tile (= C/D col, B col)
    const int q    = lane >> 4;            // quad: k-block for A/B, row-block for C
    const int batch = blockIdx.x * 16 + n;

    // zero LDS tile: h(t=0)=0, pad slots stay 0 forever
    for (int i = lane; i < 16 * TSTRIDE; i += 64) tile[i] = 0;

    // ---- A fragments (weights+bias), bf16, loaded once ----
    // lane holds A[r = 16T + n][k = q*8 + j], j=0..7
    bf16x8 afrag[7];
    #pragma unroll
    for (int T = 0; T < 7; ++T) {
        #pragma unroll
        for (int j = 0; j < 8; ++j) {
            const int k = q * 8 + j;
            const int r = 16 * T + n;
            const int u = r >> 2, g = r & 3;
            float v = 0.0f;
            if (u < HSZ) {
                const int orow = g * HSZ + u;          // original i,f,g,o row order
                if (k < ISZ)            v = w_ih[orow * ISZ + k];
                else if (k == ISZ)      v = b_ih[orow] + b_hh[orow];
                else if (k < 4 + HSZ)   v = w_hh[orow * HSZ + (k - 4)];
            }
            afrag[T][j] = to_bf16(v);
        }
    }

    const float* __restrict__ xp = x + (size_t)batch * (TSTEPS * ISZ);
    float xa0 = xp[0], xa1 = xp[1], xa2 = xp[2];   // prefetch t=0

    float c[7] = {0, 0, 0, 0, 0, 0, 0};
    float h[7] = {0, 0, 0, 0, 0, 0, 0};
    const bool isq0 = (q == 0);
    short* const myrow = &tile[n * TSTRIDE];

    __asm__ volatile("" ::: "memory");
    __builtin_amdgcn_wave_barrier();

    #pragma unroll 1
    for (int t = 0; t < TSTEPS; ++t) {
        // prefetch next step's x (consumed next iteration -> latency hidden)
        const int tn = (t + 1 < TSTEPS) ? (t + 1) * ISZ : t * ISZ;
        const float xn0 = xp[tn + 0], xn1 = xp[tn + 1], xn2 = xp[tn + 2];

        // B fragment: lane holds B[k = q*8+j][n]
        bf16x8 bfrag = *reinterpret_cast<const bf16x8*>(myrow + q * 8);
        if (isq0) {                       // slots 0..3 = x0,x1,x2,1.0 in-register
            bfrag[0] = to_bf16(xa0);
            bfrag[1] = to_bf16(xa1);
            bfrag[2] = to_bf16(xa2);
            bfrag[3] = (short)0x3F80;     // bf16(1.0)
        }

        f32x4 acc[7];
        #pragma unroll
        for (int T = 0; T < 7; ++T)
            acc[T] = __builtin_amdgcn_mfma_f32_16x16x32_bf16(
                afrag[T], bfrag, (f32x4){0.f, 0.f, 0.f, 0.f}, 0, 0, 0);

        // lane's acc[T] regs = gates i,f,g,o of unit u=4T+q, batch n
        #pragma unroll
        for (int T = 0; T < 7; ++T) {
            const float iv = fast_sigmoid(acc[T][0]);
            const float fv = fast_sigmoid(acc[T][1]);
            const float gv = fast_tanh(acc[T][2]);
            const float ov = fast_sigmoid(acc[T][3]);
            c[T] = fmaf(fv, c[T], iv * gv);
            h[T] = ov * fast_tanh(c[T]);
        }

        // write h back to LDS (bf16), unit u=4T+q -> slot 4+u of row n
        #pragma unroll
        for (int T = 0; T < 7; ++T) {
            const int u = 4 * T + q;
            if (u < HSZ) myrow[4 + u] = to_bf16(h[T]);
        }

        xa0 = xn0; xa1 = xn1; xa2 = xn2;
        __asm__ volatile("" ::: "memory");
        __builtin_amdgcn_wave_barrier();
    }

    // ---- final linear: out[b] = sum_u w_lin[u]*h[u] + b_lin ----
    float v = 0.0f;
    #pragma unroll
    for (int T = 0; T < 7; ++T) {
        const int u = 4 * T + q;
        const float wl = (u < HSZ) ? w_lin[u] : 0.0f;
        v = fmaf(wl, h[T], v);
    }
    v += __shfl_xor(v, 16);
    v += __shfl_xor(v, 32);
    if (isq0) out[batch] = v + b_lin[0];
}

extern "C" void kernel_launch(void* const* d_in, const int* in_sizes, int n_in,
                              void* d_out, int out_size, void* d_ws, size_t ws_size,
                              hipStream_t stream) {
    const float* x     = (const float*)d_in[0];
    const float* w_ih  = (const float*)d_in[1];
    const float* w_hh  = (const float*)d_in[2];
    const float* b_ih  = (const float*)d_in[3];
    const float* b_hh  = (const float*)d_in[4];
    const float* w_lin = (const float*)d_in[5];
    const float* b_lin = (const float*)d_in[6];
    float* out = (float*)d_out;

    lstm_mfma<<<NTILES, 64, 0, stream>>>(x, w_ih, w_hh, b_ih, b_hh,
                                         w_lin, b_lin, out);
}

// Round 4
// 445.721 us; speedup vs baseline: 1.2808x; 1.0119x over previous
//
#include <hip/hip_runtime.h>
#include <hip/hip_bf16.h>

// LSTM B=8192,T=512,I=3,H=25 + linear[H->1], bf16 MFMA 16x16x32.
// One wave per 16-batch tile (512 waves). R4 vs R3: R3 stalled ~1000 cy/step
// on exposed latency (1 wave/SIMD): per-step scattered global x loads and a
// serialized h LDS write->read roundtrip. Fix:
//  - ALL of x for the tile staged to LDS once, pre-packed as bf16 B-frag
//    dwords [t][n] (64 KB): loop-time x = one broadcast ds_read_b64,
//    prefetched one step ahead, zero conversion in the loop.
//  - h writes interleaved with per-unit activations (issue ASAP), single
//    ds_read_b128 latency exposed per step.
// A = W' [112x32] rows r=4u+g so one lane's 4 acc regs = i,f,g,o of unit
// u=4T+q; weights live in 7 bf16x8 frags, loaded once (register-resident).

#define TSTEPS 512
#define ISZ 3
#define HSZ 25
#define NTILES 512
#define TSTRIDE 40          // shorts per batch row in h-exchange LDS

typedef __attribute__((ext_vector_type(8))) short bf16x8;
typedef __attribute__((ext_vector_type(4))) float f32x4;

__device__ __forceinline__ float fast_sigmoid(float x) {
    float e = __builtin_amdgcn_exp2f(-1.442695040888963f * x);
    return __builtin_amdgcn_rcpf(1.0f + e);
}
__device__ __forceinline__ float fast_tanh(float x) {
    return fmaf(2.0f, fast_sigmoid(2.0f * x), -1.0f);
}
__device__ __forceinline__ unsigned short bf16_bits(float v) {
    return __builtin_bit_cast(unsigned short, __float2bfloat16(v));
}
__device__ __forceinline__ unsigned int pack_bf16(float lo, float hi) {
    return ((unsigned int)bf16_bits(hi) << 16) | (unsigned int)bf16_bits(lo);
}

__global__ __launch_bounds__(64) void lstm_mfma(
    const float* __restrict__ x,      // [B, T, I]
    const float* __restrict__ w_ih,   // [4H, I]
    const float* __restrict__ w_hh,   // [4H, H]
    const float* __restrict__ b_ih,   // [4H]
    const float* __restrict__ b_hh,   // [4H]
    const float* __restrict__ w_lin,  // [1, H]
    const float* __restrict__ b_lin,  // [1]
    float* __restrict__ out)          // [B, 1]
{
    __shared__ uint2 xpk[TSTEPS * 16];     // 64 KB: packed {pk(x0,x1), pk(x2,1)}
    __shared__ short tile[16 * TSTRIDE];   // h exchange rows (b16 slots k=0..31)

    const int lane = threadIdx.x;          // 0..63
    const int n    = lane & 15;            // batch within tile
    const int q    = lane >> 4;            // quad
    const int batch = blockIdx.x * 16 + n;
    const bool isq0 = (q == 0);

    // ---- zero h-exchange rows (pad slots stay 0 forever) ----
    for (int i = lane; i < 16 * TSTRIDE; i += 64) tile[i] = 0;

    // ---- stage + pre-pack ALL x for this tile into LDS (one time) ----
    {
        const int bsel = lane >> 2, sub4 = lane & 3;
        const float* __restrict__ g = x + (size_t)(blockIdx.x * 16 + bsel) * (TSTEPS * ISZ);
        #pragma unroll 4
        for (int it = 0; it < 32; ++it) {
            const int tg = sub4 + 4 * it;            // group of 4 steps
            const float4* f4 = (const float4*)(g + tg * 12);
            float4 a = f4[0], b4 = f4[1], c4 = f4[2];
            const float s[4][3] = { {a.x, a.y, a.z}, {a.w, b4.x, b4.y},
                                    {b4.z, b4.w, c4.x}, {c4.y, c4.z, c4.w} };
            #pragma unroll
            for (int u = 0; u < 4; ++u) {
                const int t = tg * 4 + u;
                uint2 d;
                d.x = pack_bf16(s[u][0], s[u][1]);
                d.y = pack_bf16(s[u][2], 1.0f);
                xpk[t * 16 + bsel] = d;
            }
        }
    }

    // ---- A fragments (weights+bias), bf16, loaded once ----
    bf16x8 afrag[7];
    #pragma unroll
    for (int T = 0; T < 7; ++T) {
        #pragma unroll
        for (int j = 0; j < 8; ++j) {
            const int k = q * 8 + j;
            const int r = 16 * T + n;
            const int u = r >> 2, g = r & 3;
            float v = 0.0f;
            if (u < HSZ) {
                const int orow = g * HSZ + u;        // i,f,g,o row order
                if (k < ISZ)            v = w_ih[orow * ISZ + k];
                else if (k == ISZ)      v = b_ih[orow] + b_hh[orow];
                else if (k < 4 + HSZ)   v = w_hh[orow * HSZ + (k - 4)];
            }
            afrag[T][j] = (short)bf16_bits(v);
        }
    }

    float c[7] = {0, 0, 0, 0, 0, 0, 0};
    float h[7] = {0, 0, 0, 0, 0, 0, 0};
    short* const myrow = &tile[n * TSTRIDE];

    __asm__ volatile("" ::: "memory");
    __builtin_amdgcn_wave_barrier();

    uint2 xdw = xpk[n];                    // t=0 (broadcast across quads)

    #pragma unroll 1
    for (int t = 0; t < TSTEPS; ++t) {
        // prefetch next step's packed x (independent of everything)
        const int tn = (t + 1 < TSTEPS) ? t + 1 : t;
        const uint2 xnxt = xpk[tn * 16 + n];

        // B fragment: h part from LDS, x part overlaid for quad 0
        bf16x8 bfrag = *reinterpret_cast<const bf16x8*>(myrow + q * 8);
        {
            uint4 bi = __builtin_bit_cast(uint4, bfrag);
            if (isq0) { bi.x = xdw.x; bi.y = xdw.y; }
            bfrag = __builtin_bit_cast(bf16x8, bi);
        }

        f32x4 acc[7];
        #pragma unroll
        for (int T = 0; T < 7; ++T)
            acc[T] = __builtin_amdgcn_mfma_f32_16x16x32_bf16(
                afrag[T], bfrag, (f32x4){0.f, 0.f, 0.f, 0.f}, 0, 0, 0);

        // activations per unit; write h[T] to LDS the moment it's ready
        #pragma unroll
        for (int T = 0; T < 7; ++T) {
            const float iv = fast_sigmoid(acc[T][0]);
            const float fv = fast_sigmoid(acc[T][1]);
            const float gv = fast_tanh(acc[T][2]);
            const float ov = fast_sigmoid(acc[T][3]);
            c[T] = fmaf(fv, c[T], iv * gv);
            h[T] = ov * fast_tanh(c[T]);
            const int u = 4 * T + q;
            if (T < 6 || u < HSZ)
                myrow[4 + u] = (short)bf16_bits(h[T]);
        }

        xdw = xnxt;
        __asm__ volatile("" ::: "memory");
        __builtin_amdgcn_wave_barrier();
    }

    // ---- final linear: out[b] = sum_u w_lin[u]*h[u] + b_lin ----
    float v = 0.0f;
    #pragma unroll
    for (int T = 0; T < 7; ++T) {
        const int u = 4 * T + q;
        const float wl = (u < HSZ) ? w_lin[u] : 0.0f;
        v = fmaf(wl, h[T], v);
    }
    v += __shfl_xor(v, 16);
    v += __shfl_xor(v, 32);
    if (isq0) out[batch] = v + b_lin[0];
}

extern "C" void kernel_launch(void* const* d_in, const int* in_sizes, int n_in,
                              void* d_out, int out_size, void* d_ws, size_t ws_size,
                              hipStream_t stream) {
    const float* x     = (const float*)d_in[0];
    const float* w_ih  = (const float*)d_in[1];
    const float* w_hh  = (const float*)d_in[2];
    const float* b_ih  = (const float*)d_in[3];
    const float* b_hh  = (const float*)d_in[4];
    const float* w_lin = (const float*)d_in[5];
    const float* b_lin = (const float*)d_in[6];
    float* out = (float*)d_out;

    lstm_mfma<<<NTILES, 64, 0, stream>>>(x, w_ih, w_hh, b_ih, b_hh,
                                         w_lin, b_lin, out);
}

// Round 5
// 302.988 us; speedup vs baseline: 1.8842x; 1.4711x over previous
//
#include <hip/hip_runtime.h>
#include <hip/hip_bf16.h>

// LSTM B=8192,T=512,I=3,H=25 + linear[H->1], bf16 MFMA 16x16x32.
// R5: one 256-thread block (4 waves) per 16-batch tile -> 2048 waves = 2/SIMD
// on every SIMD (R3/R4 had 512 single-wave blocks: half the SIMDs idle, zero
// latency hiding -> 1780 cy/step vs ~700 cy of pipe work). Wave w owns MFMA
// frags T=2w,2w+1 (wave 3: T=6 only): no redundant MFMA, 4x less issue/wave.
// h exchanged via double-buffered LDS rows, ONE __syncthreads per step.
// Activations: fused-denominator form, 8 trans/unit (was 10):
//   sigmoid(a)*tanh(b) = (1-e_b) * rcp((1+e_a)(1+e_b)),  e_z = exp2(-k z)
// with fmin clamp on doubled-arg exps (inf-inf NaN guard for |c| tails).

#define TSTEPS 512
#define ISZ 3
#define HSZ 25
#define NTILES 512
#define TSTRIDE 40          // shorts per batch row (80 B, 16B aligned)

typedef __attribute__((ext_vector_type(8))) short bf16x8;
typedef __attribute__((ext_vector_type(4))) float f32x4;

__device__ __forceinline__ unsigned short bf16_bits(float v) {
    return __builtin_bit_cast(unsigned short, __float2bfloat16(v));
}
__device__ __forceinline__ unsigned int pack_bf16(float lo, float hi) {
    return ((unsigned int)bf16_bits(hi) << 16) | (unsigned int)bf16_bits(lo);
}

// 8-trans LSTM cell update: c' = sig(a1)*c + sig(a0)*tanh(a2); h = sig(a3)*tanh(c')
__device__ __forceinline__ void lstm_act(const f32x4 acc, float& c, float& h) {
    const float K1 = 1.442695040888963f;   // log2 e
    const float K2 = 2.885390081777927f;   // 2 log2 e
    const float e0 = __builtin_amdgcn_exp2f(-K1 * acc[0]);
    const float e1 = __builtin_amdgcn_exp2f(-K1 * acc[1]);
    const float e2 = __builtin_amdgcn_exp2f(fminf(-K2 * acc[2], 126.0f));
    const float e3 = __builtin_amdgcn_exp2f(-K1 * acc[3]);
    const float f  = __builtin_amdgcn_rcpf(1.0f + e1);
    const float ig = (1.0f - e2) * __builtin_amdgcn_rcpf((1.0f + e0) * (1.0f + e2));
    c = fmaf(f, c, ig);
    const float ec = __builtin_amdgcn_exp2f(fminf(-K2 * c, 126.0f));
    h = (1.0f - ec) * __builtin_amdgcn_rcpf((1.0f + e3) * (1.0f + ec));
}

__global__ __launch_bounds__(256) void lstm_mfma(
    const float* __restrict__ x,      // [B, T, I]
    const float* __restrict__ w_ih,   // [4H, I]
    const float* __restrict__ w_hh,   // [4H, H]
    const float* __restrict__ b_ih,   // [4H]
    const float* __restrict__ b_hh,   // [4H]
    const float* __restrict__ w_lin,  // [1, H]
    const float* __restrict__ b_lin,  // [1]
    float* __restrict__ out)          // [B, 1]
{
    __shared__ uint2 xpk[TSTEPS * 16];        // 64 KB packed bf16 x (+1.0)
    __shared__ short hb[2][16 * TSTRIDE];     // double-buffered h rows (2.5 KB)
    __shared__ float outred[4][16];

    const int tid  = threadIdx.x;
    const int w    = tid >> 6;       // wave 0..3: owns T = 2w (+2w+1 if w<3)
    const int lane = tid & 63;
    const int n    = lane & 15;      // batch within tile
    const int q    = lane >> 4;      // quad
    const bool isq0 = (q == 0);

    // zero both h buffers (h(0)=0; pad slots stay 0 forever)
    for (int i = tid; i < 2 * 16 * TSTRIDE; i += 256) ((short*)hb)[i] = 0;

    // ---- stage + pre-pack ALL x for this tile (one time, 4 waves) ----
    {
        const int bsel = tid >> 4, sub16 = tid & 15;   // 16 threads per batch
        const float* __restrict__ g = x + (size_t)(blockIdx.x * 16 + bsel) * (TSTEPS * ISZ);
        #pragma unroll
        for (int it = 0; it < 8; ++it) {
            const int tg = sub16 + 16 * it;            // 4-step group 0..127
            const float4* f4 = (const float4*)(g + tg * 12);
            float4 a = f4[0], b4 = f4[1], c4 = f4[2];
            const float s[4][3] = { {a.x, a.y, a.z}, {a.w, b4.x, b4.y},
                                    {b4.z, b4.w, c4.x}, {c4.y, c4.z, c4.w} };
            #pragma unroll
            for (int u = 0; u < 4; ++u) {
                uint2 d;
                d.x = pack_bf16(s[u][0], s[u][1]);
                d.y = pack_bf16(s[u][2], 1.0f);
                xpk[(tg * 4 + u) * 16 + bsel] = d;
            }
        }
    }

    // ---- A fragments for this wave's T-set (loaded once, register-resident) ----
    // A[r=16T+n][k=q*8+j]; row r=4u+g (unit-major); k: [w_ih 0..2, bias 3, w_hh 4..28, 0 pad]
    bf16x8 afrag[2];
    #pragma unroll
    for (int idx = 0; idx < 2; ++idx) {
        const int T = 2 * w + idx;                     // T=7 (w=3,idx=1) -> zeros, unused
        #pragma unroll
        for (int j = 0; j < 8; ++j) {
            const int k = q * 8 + j;
            const int r = 16 * T + n;
            const int u = r >> 2, g = r & 3;
            float v = 0.0f;
            if (u < HSZ) {
                const int orow = g * HSZ + u;          // original i,f,g,o row order
                if (k < ISZ)            v = w_ih[orow * ISZ + k];
                else if (k == ISZ)      v = b_ih[orow] + b_hh[orow];
                else if (k < 4 + HSZ)   v = w_hh[orow * HSZ + (k - 4)];
            }
            afrag[idx][j] = (short)bf16_bits(v);
        }
    }

    __syncthreads();

    float c0 = 0.f, c1 = 0.f, h0 = 0.f, h1 = 0.f;

    #pragma unroll 1
    for (int t = 0; t < TSTEPS; ++t) {
        const short* __restrict__ rrow = &hb[t & 1][n * TSTRIDE];
        short* __restrict__ wrow = &hb[(t + 1) & 1][n * TSTRIDE];

        const uint2 xdw = xpk[t * 16 + n];
        bf16x8 bfrag = *reinterpret_cast<const bf16x8*>(rrow + q * 8);
        {
            uint4 bi = __builtin_bit_cast(uint4, bfrag);
            if (isq0) { bi.x = xdw.x; bi.y = xdw.y; }
            bfrag = __builtin_bit_cast(bf16x8, bi);
        }

        // MFMAs first (both in flight), then activations
        f32x4 acc0 = __builtin_amdgcn_mfma_f32_16x16x32_bf16(
            afrag[0], bfrag, (f32x4){0.f, 0.f, 0.f, 0.f}, 0, 0, 0);
        f32x4 acc1;
        if (w < 3)
            acc1 = __builtin_amdgcn_mfma_f32_16x16x32_bf16(
                afrag[1], bfrag, (f32x4){0.f, 0.f, 0.f, 0.f}, 0, 0, 0);

        lstm_act(acc0, c0, h0);                        // unit u = 8w + q
        if (w < 3 || isq0)
            wrow[4 + 8 * w + q] = (short)bf16_bits(h0);
        if (w < 3) {
            lstm_act(acc1, c1, h1);                    // unit u = 8w + 4 + q (<24)
            wrow[4 + 8 * w + 4 + q] = (short)bf16_bits(h1);
        }

        __syncthreads();
    }

    // ---- final linear: out[b] = sum_u w_lin[u]*h[u] + b_lin ----
    float v = 0.f;
    {
        const int u0 = 8 * w + q;
        if (u0 < HSZ) v = w_lin[u0] * h0;
        if (w < 3)    v = fmaf(w_lin[8 * w + 4 + q], h1, v);
    }
    v += __shfl_xor(v, 16);
    v += __shfl_xor(v, 32);
    if (lane < 16) outred[w][lane] = v;
    __syncthreads();
    if (tid < 16)
        out[blockIdx.x * 16 + tid] =
            outred[0][tid] + outred[1][tid] + outred[2][tid] + outred[3][tid] + b_lin[0];
}

extern "C" void kernel_launch(void* const* d_in, const int* in_sizes, int n_in,
                              void* d_out, int out_size, void* d_ws, size_t ws_size,
                              hipStream_t stream) {
    const float* x     = (const float*)d_in[0];
    const float* w_ih  = (const float*)d_in[1];
    const float* w_hh  = (const float*)d_in[2];
    const float* b_ih  = (const float*)d_in[3];
    const float* b_hh  = (const float*)d_in[4];
    const float* w_lin = (const float*)d_in[5];
    const float* b_lin = (const float*)d_in[6];
    float* out = (float*)d_out;

    lstm_mfma<<<NTILES, 256, 0, stream>>>(x, w_ih, w_hh, b_ih, b_hh,
                                          w_lin, b_lin, out);
}

// Round 6
// 301.563 us; speedup vs baseline: 1.8931x; 1.0047x over previous
//
#include <hip/hip_runtime.h>
#include <hip/hip_bf16.h>

// LSTM B=8192,T=512,I=3,H=25 + linear[H->1], bf16 MFMA 16x16x32.
// R6: 7 waves per 16-batch tile (448-thread block), wave w owns exactly ONE
// MFMA fragment T=w (units 4w..4w+3, one unit per quad per lane).
// 512 blocks x 7 waves = 3584 waves = 3.5/SIMD (R5 had 2/SIMD and 45% of the
// wall was exposed latency). Per-wave issue/step: 1 MFMA + 8 trans + ~50cy glue.
// h exchanged via double-buffered LDS rows, one __syncthreads per step.
// x pre-packed to bf16 B-frag dwords in LDS once (by waves 0-3; waves 4-6
// load their A frags meanwhile).

#define TSTEPS 512
#define ISZ 3
#define HSZ 25
#define NTILES 512
#define NW 7
#define TSTRIDE 40          // shorts per batch row (80 B, 16B aligned)

typedef __attribute__((ext_vector_type(8))) short bf16x8;
typedef __attribute__((ext_vector_type(4))) float f32x4;

__device__ __forceinline__ unsigned short bf16_bits(float v) {
    return __builtin_bit_cast(unsigned short, __float2bfloat16(v));
}
__device__ __forceinline__ unsigned int pack_bf16(float lo, float hi) {
    return ((unsigned int)bf16_bits(hi) << 16) | (unsigned int)bf16_bits(lo);
}

// 8-trans LSTM cell: c' = sig(a1)*c + sig(a0)*tanh(a2); h = sig(a3)*tanh(c')
__device__ __forceinline__ void lstm_act(const f32x4 acc, float& c, float& h) {
    const float K1 = 1.442695040888963f;   // log2 e
    const float K2 = 2.885390081777927f;   // 2 log2 e
    const float e0 = __builtin_amdgcn_exp2f(-K1 * acc[0]);
    const float e1 = __builtin_amdgcn_exp2f(-K1 * acc[1]);
    const float e2 = __builtin_amdgcn_exp2f(fminf(-K2 * acc[2], 126.0f));
    const float e3 = __builtin_amdgcn_exp2f(-K1 * acc[3]);
    const float f  = __builtin_amdgcn_rcpf(1.0f + e1);
    const float ig = (1.0f - e2) * __builtin_amdgcn_rcpf((1.0f + e0) * (1.0f + e2));
    c = fmaf(f, c, ig);
    const float ec = __builtin_amdgcn_exp2f(fminf(-K2 * c, 126.0f));
    h = (1.0f - ec) * __builtin_amdgcn_rcpf((1.0f + e3) * (1.0f + ec));
}

__global__ __launch_bounds__(NW * 64) void lstm_mfma(
    const float* __restrict__ x,      // [B, T, I]
    const float* __restrict__ w_ih,   // [4H, I]
    const float* __restrict__ w_hh,   // [4H, H]
    const float* __restrict__ b_ih,   // [4H]
    const float* __restrict__ b_hh,   // [4H]
    const float* __restrict__ w_lin,  // [1, H]
    const float* __restrict__ b_lin,  // [1]
    float* __restrict__ out)          // [B, 1]
{
    __shared__ uint2 xpk[TSTEPS * 16];        // 64 KB packed bf16 x (+1.0)
    __shared__ short hb[2][16 * TSTRIDE];     // double-buffered h rows (2.5 KB)
    __shared__ float outred[NW][16];

    const int tid  = threadIdx.x;
    const int w    = tid >> 6;       // wave 0..6: owns frag T=w (units 4w..4w+3)
    const int lane = tid & 63;
    const int n    = lane & 15;      // batch within tile
    const int q    = lane >> 4;      // quad -> unit u = 4w + q
    const bool isq0 = (q == 0);
    const int u    = 4 * w + q;

    // zero both h buffers (h(0)=0; pad slots stay 0 forever)
    for (int i = tid; i < 2 * 16 * TSTRIDE; i += NW * 64) ((short*)hb)[i] = 0;

    // ---- stage + pre-pack ALL x for this tile (waves 0-3 only) ----
    if (tid < 256) {
        const int bsel = tid >> 4, sub16 = tid & 15;   // 16 threads per batch
        const float* __restrict__ g = x + (size_t)(blockIdx.x * 16 + bsel) * (TSTEPS * ISZ);
        #pragma unroll
        for (int it = 0; it < 8; ++it) {
            const int tg = sub16 + 16 * it;            // 4-step group 0..127
            const float4* f4 = (const float4*)(g + tg * 12);
            float4 a = f4[0], b4 = f4[1], c4 = f4[2];
            const float s[4][3] = { {a.x, a.y, a.z}, {a.w, b4.x, b4.y},
                                    {b4.z, b4.w, c4.x}, {c4.y, c4.z, c4.w} };
            #pragma unroll
            for (int uu = 0; uu < 4; ++uu) {
                uint2 d;
                d.x = pack_bf16(s[uu][0], s[uu][1]);
                d.y = pack_bf16(s[uu][2], 1.0f);
                xpk[(tg * 4 + uu) * 16 + bsel] = d;
            }
        }
    }

    // ---- this wave's A fragment (loaded once, register-resident) ----
    // A[r=16w+n][k=q*8+j]; row r=4u'+g (unit-major); k: [w_ih 0..2, bias 3, w_hh 4..28]
    bf16x8 afrag;
    #pragma unroll
    for (int j = 0; j < 8; ++j) {
        const int k = q * 8 + j;
        const int r = 16 * w + n;
        const int uu = r >> 2, g = r & 3;
        float v = 0.0f;
        if (uu < HSZ) {
            const int orow = g * HSZ + uu;             // original i,f,g,o row order
            if (k < ISZ)            v = w_ih[orow * ISZ + k];
            else if (k == ISZ)      v = b_ih[orow] + b_hh[orow];
            else if (k < 4 + HSZ)   v = w_hh[orow * HSZ + (k - 4)];
        }
        afrag[j] = (short)bf16_bits(v);
    }

    __syncthreads();

    float c = 0.f, h = 0.f;
    uint2 xdw = xpk[n];                                // t=0

    #pragma unroll 1
    for (int t = 0; t < TSTEPS; ++t) {
        // prefetch next step's packed x (xpk is read-only: no barrier dep)
        const int tn = (t + 1 < TSTEPS) ? t + 1 : t;
        const uint2 xnxt = xpk[tn * 16 + n];

        const short* __restrict__ rrow = &hb[t & 1][n * TSTRIDE];
        short* __restrict__ wrow = &hb[(t + 1) & 1][n * TSTRIDE];

        bf16x8 bfrag = *reinterpret_cast<const bf16x8*>(rrow + q * 8);
        {
            uint4 bi = __builtin_bit_cast(uint4, bfrag);
            if (isq0) { bi.x = xdw.x; bi.y = xdw.y; }
            bfrag = __builtin_bit_cast(bf16x8, bi);
        }

        const f32x4 acc = __builtin_amdgcn_mfma_f32_16x16x32_bf16(
            afrag, bfrag, (f32x4){0.f, 0.f, 0.f, 0.f}, 0, 0, 0);

        lstm_act(acc, c, h);                           // unit u, batch n

        if (w < 6 || isq0)                             // u < 25
            wrow[4 + u] = (short)bf16_bits(h);

        xdw = xnxt;
        __syncthreads();
    }

    // ---- final linear: out[b] = sum_u w_lin[u]*h[u] + b_lin ----
    float v = 0.f;
    if (w < 6 || isq0) v = w_lin[u] * h;
    v += __shfl_xor(v, 16);
    v += __shfl_xor(v, 32);
    if (lane < 16) outred[w][lane] = v;
    __syncthreads();
    if (tid < 16) {
        float s = b_lin[0];
        #pragma unroll
        for (int k = 0; k < NW; ++k) s += outred[k][tid];
        out[blockIdx.x * 16 + tid] = s;
    }
}

extern "C" void kernel_launch(void* const* d_in, const int* in_sizes, int n_in,
                              void* d_out, int out_size, void* d_ws, size_t ws_size,
                              hipStream_t stream) {
    const float* x     = (const float*)d_in[0];
    const float* w_ih  = (const float*)d_in[1];
    const float* w_hh  = (const float*)d_in[2];
    const float* b_ih  = (const float*)d_in[3];
    const float* b_hh  = (const float*)d_in[4];
    const float* w_lin = (const float*)d_in[5];
    const float* b_lin = (const float*)d_in[6];
    float* out = (float*)d_out;

    lstm_mfma<<<NTILES, NW * 64, 0, stream>>>(x, w_ih, w_hh, b_ih, b_hh,
                                              w_lin, b_lin, out);
}